// Round 2
// baseline (8070.639 us; speedup 1.0000x reference)
//
#include <hip/hip_runtime.h>
#include <hip/hip_bf16.h>
#include <cstdint>
#include <cstddef>

typedef __bf16 bf16;
typedef bf16 bf16x8 __attribute__((ext_vector_type(8)));
typedef bf16 bf16x4 __attribute__((ext_vector_type(4)));
typedef float f32x16 __attribute__((ext_vector_type(16)));
typedef float f32x4 __attribute__((ext_vector_type(4)));
typedef unsigned int u32;
typedef unsigned short u16;

#define NB 64
#define NT 512
#define NIN 256
#define NH 512

// ---------------- setup kernels ----------------

// f32 -> (hi, lo) bf16 split, vectorized x4
__global__ __launch_bounds__(256) void k_cvt_hl(const float4* __restrict__ src,
                                                bf16x4* __restrict__ dhi,
                                                bf16x4* __restrict__ dlo, int n4) {
  int i = blockIdx.x * 256 + threadIdx.x;
  int st = gridDim.x * 256;
  for (; i < n4; i += st) {
    float4 f = src[i];
    bf16x4 h, l;
    h[0] = (bf16)f.x; l[0] = (bf16)(f.x - (float)h[0]);
    h[1] = (bf16)f.y; l[1] = (bf16)(f.y - (float)h[1]);
    h[2] = (bf16)f.z; l[2] = (bf16)(f.z - (float)h[2]);
    h[3] = (bf16)f.w; l[3] = (bf16)(f.w - (float)h[3]);
    dhi[i] = h; dlo[i] = l;
  }
}

// Wm (512 x 1024) -> Wmh(hi/lo) [o][k]=Wm[o][512+k], WmhT(hi/lo) [j][k]=Wm[k][512+j],
//                    Wg(hi/lo)  [o][k]=Wm[o][k]   (all 512x512)
__global__ __launch_bounds__(256) void k_cvt_wm(const float* __restrict__ Wm,
                                                bf16* __restrict__ WmhH, bf16* __restrict__ WmhL,
                                                bf16* __restrict__ WmhTH, bf16* __restrict__ WmhTL,
                                                bf16* __restrict__ WgH, bf16* __restrict__ WgL) {
  int i = blockIdx.x * 256 + threadIdx.x;  // 262144 total
  int a = i >> 9, b = i & 511;
  float w1 = Wm[a * 1024 + 512 + b];
  float w2 = Wm[a * 1024 + b];
  float w3 = Wm[b * 1024 + 512 + a];
  bf16 h;
  h = (bf16)w1; WmhH[i] = h;  WmhL[i]  = (bf16)(w1 - (float)h);
  h = (bf16)w2; WgH[i] = h;   WgL[i]   = (bf16)(w2 - (float)h);
  h = (bf16)w3; WmhTH[i] = h; WmhTL[i] = (bf16)(w3 - (float)h);
}

// C[m][n] = sum_k A[m][k]*B[n][k] (+bias[n]); hi/lo 3-product; f32 and/or hi/lo bf16 out.
__global__ __launch_bounds__(256) void k_gemm(const bf16* __restrict__ Ahi, const bf16* __restrict__ Alo,
                                              int lda,
                                              const bf16* __restrict__ Bhi, const bf16* __restrict__ Blo,
                                              int ldb,
                                              const float* __restrict__ bias,
                                              float* __restrict__ outf,
                                              bf16* __restrict__ outhi, bf16* __restrict__ outlo,
                                              int ldc, int K) {
  int tid = threadIdx.x;
  int wave = tid >> 6, lane = tid & 63;
  int wm = wave >> 1, wn = wave & 1;
  int row0 = blockIdx.y * 64 + wm * 32 + (lane & 31);
  int col0 = blockIdx.x * 64 + wn * 32 + (lane & 31);
  int kk = (lane >> 5) * 8;
  const bf16* ah = Ahi + (size_t)row0 * lda + kk;
  const bf16* al = Alo + (size_t)row0 * lda + kk;
  const bf16* bh = Bhi + (size_t)col0 * ldb + kk;
  const bf16* bl = Blo + (size_t)col0 * ldb + kk;
  f32x16 acc;
#pragma unroll
  for (int i = 0; i < 16; ++i) acc[i] = 0.f;
  for (int ks = 0; ks < K / 16; ++ks) {
    bf16x8 a0 = *(const bf16x8*)(ah + ks * 16);
    bf16x8 a1 = *(const bf16x8*)(al + ks * 16);
    bf16x8 b0 = *(const bf16x8*)(bh + ks * 16);
    bf16x8 b1 = *(const bf16x8*)(bl + ks * 16);
    acc = __builtin_amdgcn_mfma_f32_32x32x16_bf16(a0, b0, acc, 0, 0, 0);
    acc = __builtin_amdgcn_mfma_f32_32x32x16_bf16(a1, b0, acc, 0, 0, 0);
    acc = __builtin_amdgcn_mfma_f32_32x32x16_bf16(a0, b1, acc, 0, 0, 0);
  }
  int col = blockIdx.x * 64 + wn * 32 + (lane & 31);
  int rowb = blockIdx.y * 64 + wm * 32;
  float bv = bias ? bias[col] : 0.f;
#pragma unroll
  for (int j = 0; j < 16; ++j) {
    int row = rowb + (j & 3) + 8 * (j >> 2) + 4 * (lane >> 5);
    float v = acc[j] + bv;
    size_t o = (size_t)row * ldc + col;
    if (outf) outf[o] = v;
    if (outhi) { bf16 h = (bf16)v; outhi[o] = h; outlo[o] = (bf16)(v - (float)h); }
  }
}

// ---------------- main scan kernel ----------------

__device__ __forceinline__ void wave_poll(const u32* f, int lane, unsigned tgt) {
  for (;;) {
    unsigned v = __hip_atomic_load(f + lane, __ATOMIC_RELAXED, __HIP_MEMORY_SCOPE_AGENT);
    if (__all((int)(v >= tgt))) return;
    __builtin_amdgcn_s_sleep(1);
  }
}

// grid 128: blocks 0..63 = stage 0 (layer 0), 64..127 = stage 1 (layer 1, one step behind).
// Each WG owns 8 gate-columns. Weights (hi/lo) live in 256 VGPRs/lane for the whole scan.
// h state: global rings, hi plane + lo plane (+32768 elems), written with device-scope
// (L2-bypass) u32 stores; flags: one word per WG, polled one-flag-per-lane by one wave.
__global__ __launch_bounds__(256, 1) void k_scan(
    const bf16* __restrict__ xhi, const bf16* __restrict__ xlo,
    const bf16* __restrict__ Wm0hH, const bf16* __restrict__ Wm0hL,
    const bf16* __restrict__ Whc0H, const bf16* __restrict__ Whc0L,
    const bf16* __restrict__ Wx0H, const bf16* __restrict__ Wx0L,
    const bf16* __restrict__ Wm1hH, const bf16* __restrict__ Wm1hL,
    const bf16* __restrict__ Whc1H, const bf16* __restrict__ Whc1L,
    const bf16* __restrict__ Wx1H, const bf16* __restrict__ Wx1L,
    const float* __restrict__ gm0f, const float* __restrict__ ghb0f, const float* __restrict__ bx0,
    const float* __restrict__ gm1f, const float* __restrict__ ghb1f, const float* __restrict__ bx1,
    bf16* __restrict__ h0ring,   // [4 slots][hi|lo][64][512]
    bf16* __restrict__ h1ring,   // [2 slots][hi|lo][64][512]
    u32* __restrict__ flags0, u32* __restrict__ flags1,
    float* __restrict__ out) {
  __shared__ __align__(16) float RedH[32][68];
  __shared__ __align__(16) float RedX[32][68];
  __shared__ float gmL[64][8];
  __shared__ float ghbL[3][64][8];
  __shared__ float bxL[24];

  const int tid = threadIdx.x;
  const int wave = tid >> 6, lane = tid & 63;
  const bool s1 = blockIdx.x >= 64;
  const int w = s1 ? (int)blockIdx.x - 64 : (int)blockIdx.x;
  const int cb = w * 8;

  const float* gmf = s1 ? gm1f : gm0f;
  const float* ghbf = s1 ? ghb1f : ghb0f;
  const float* bxv = s1 ? bx1 : bx0;

  for (int i = tid; i < 512; i += 256) gmL[i >> 3][i & 7] = gmf[(i >> 3) * 512 + cb + (i & 7)];
  for (int i = tid; i < 1536; i += 256) {
    int g = i / 512, j = i - g * 512;
    ghbL[g][j >> 3][j & 7] = ghbf[(j >> 3) * 1536 + g * 512 + cb + (j & 7)];
  }
  if (tid < 24) bxL[tid] = bxv[(tid >> 3) * 512 + cb + (tid & 7)];

  const bool isH = wave < 2;   // waves 0,1: h-recurrence matmul; 2,3: x-path matmul
  const int mt = wave & 1;     // M-tile (batch rows 32*mt..)
  const int n = lane & 31;     // B column (packed gate row)
  const int kk8 = (lane >> 5) * 8;
  const int arow = mt * 32 + n;

  // ---- one-time: B fragments (hi+lo) into registers ----
  bf16x8 Bhi[32], Blo[32];
  bf16x8 zz;
#pragma unroll
  for (int i = 0; i < 8; ++i) zz[i] = (bf16)0.f;

  if (isH) {
    // rows: n<8 -> Wmh[cb+n]; 8..15 -> Whc[cb+n-8]; 16..23 -> Whc[512+...]; 24..31 -> Whc[1024+...]
    const bf16 *WH, *WL;
    size_t roff;
    if (n < 8) {
      WH = s1 ? Wm1hH : Wm0hH; WL = s1 ? Wm1hL : Wm0hL;
      roff = (size_t)(cb + n) * 512;
    } else {
      WH = s1 ? Whc1H : Whc0H; WL = s1 ? Whc1L : Whc0L;
      roff = (size_t)(((n >> 3) - 1) * 512 + cb + (n & 7)) * 512;
    }
#pragma unroll
    for (int ks = 0; ks < 32; ++ks) {
      Bhi[ks] = *(const bf16x8*)(WH + roff + ks * 16 + kk8);
      Blo[ks] = *(const bf16x8*)(WL + roff + ks * 16 + kk8);
    }
  } else if (s1) {
    size_t roff = n < 24 ? (size_t)((n >> 3) * 512 + cb + (n & 7)) * 512 : 0;
    bool val = n < 24;
#pragma unroll
    for (int ks = 0; ks < 32; ++ks) {
      bf16x8 bh = *(const bf16x8*)(Wx1H + roff + ks * 16 + kk8);
      bf16x8 bl = *(const bf16x8*)(Wx1L + roff + ks * 16 + kk8);
      Bhi[ks] = val ? bh : zz;
      Blo[ks] = val ? bl : zz;
    }
  } else {
    size_t roff = n < 24 ? (size_t)((n >> 3) * 512 + cb + (n & 7)) * 256 : 0;
    bool val = n < 24;
#pragma unroll
    for (int ks = 0; ks < 16; ++ks) {
      bf16x8 bh = *(const bf16x8*)(Wx0H + roff + ks * 16 + kk8);
      bf16x8 bl = *(const bf16x8*)(Wx0L + roff + ks * 16 + kk8);
      Bhi[ks] = val ? bh : zz;
      Blo[ks] = val ? bl : zz;
    }
  }

  const u32* selfF = s1 ? flags1 : flags0;
  const u32* othF  = s1 ? flags0 : flags1;
  u32* myflag = (s1 ? flags1 : flags0) + w;

  const int gb = tid >> 2, cp = tid & 3;  // gate phase: thread -> (batch gb, col pair cp)

  for (int t = 0; t < NT; ++t) {
    // waits (parallel across waves 0/1), then join
    if (wave == 0) {
      if (t > 0) wave_poll(selfF, lane, (unsigned)t);          // peers finished t-1
    } else if (wave == 1) {
      if (s1) wave_poll(othF, lane, (unsigned)(t + 1));        // h0[t] ready
      else if (t >= 4) wave_poll(othF, lane, (unsigned)(t - 3));  // ring backpressure
    }
    __syncthreads();
    __builtin_amdgcn_fence(__ATOMIC_ACQUIRE, "agent");         // invalidate L1/L2 (cross-XCD)

    f32x16 acc;
#pragma unroll
    for (int i = 0; i < 16; ++i) acc[i] = 0.f;

    if (isH || s1) {
      // A = h-state (hi plane, lo plane at +32768), K = 512
      const bf16* Ah;
      if (isH)
        Ah = (s1 ? h1ring + ((t + 1) & 1) * 65536 : h0ring + ((t + 3) & 3) * 65536)
             + arow * 512 + kk8;
      else
        Ah = h0ring + (t & 3) * 65536 + arow * 512 + kk8;   // stage-1 X: h0[t]
#pragma unroll
      for (int ks = 0; ks < 32; ++ks) {
        bf16x8 a0 = *(const bf16x8*)(Ah + ks * 16);
        bf16x8 a1 = *(const bf16x8*)(Ah + 32768 + ks * 16);
        acc = __builtin_amdgcn_mfma_f32_32x32x16_bf16(a0, Bhi[ks], acc, 0, 0, 0);
        acc = __builtin_amdgcn_mfma_f32_32x32x16_bf16(a1, Bhi[ks], acc, 0, 0, 0);
        acc = __builtin_amdgcn_mfma_f32_32x32x16_bf16(a0, Blo[ks], acc, 0, 0, 0);
      }
    } else {
      // stage-0 X: A = x[:, t, :] (hi/lo arrays), K = 256
      const bf16* Ah = xhi + (size_t)arow * (NT * NIN) + t * NIN + kk8;
      const bf16* Al = xlo + (size_t)arow * (NT * NIN) + t * NIN + kk8;
#pragma unroll
      for (int ks = 0; ks < 16; ++ks) {
        bf16x8 a0 = *(const bf16x8*)(Ah + ks * 16);
        bf16x8 a1 = *(const bf16x8*)(Al + ks * 16);
        acc = __builtin_amdgcn_mfma_f32_32x32x16_bf16(a0, Bhi[ks], acc, 0, 0, 0);
        acc = __builtin_amdgcn_mfma_f32_32x32x16_bf16(a1, Bhi[ks], acc, 0, 0, 0);
        acc = __builtin_amdgcn_mfma_f32_32x32x16_bf16(a0, Blo[ks], acc, 0, 0, 0);
      }
    }

    {  // C fragments -> LDS transpose buffer: Red[packed_col][batch_row]
      float (*Red)[68] = isH ? RedH : RedX;
#pragma unroll
      for (int rg = 0; rg < 4; ++rg) {
        f32x4 v;
        v[0] = acc[4 * rg]; v[1] = acc[4 * rg + 1];
        v[2] = acc[4 * rg + 2]; v[3] = acc[4 * rg + 3];
        *(f32x4*)&Red[n][mt * 32 + rg * 8 + ((lane >> 5) << 2)] = v;
      }
    }
    __syncthreads();

    // gate phase: thread handles (gb, c=2cp) and (gb, c=2cp+1)
    float hv[2];
#pragma unroll
    for (int e = 0; e < 2; ++e) {
      int c = 2 * cp + e;
      float hx = gmL[gb][c] + RedH[c][gb];
      float hr = ghbL[0][gb][c] + RedH[8 + c][gb];
      float hu = ghbL[1][gb][c] + RedH[16 + c][gb];
      float hn = ghbL[2][gb][c] + RedH[24 + c][gb];
      float xr = bxL[c] + RedX[c][gb];
      float xu = bxL[8 + c] + RedX[8 + c][gb];
      float xn = bxL[16 + c] + RedX[16 + c][gb];
      float r = 1.f / (1.f + __expf(-(xr + hr)));
      float u = 1.f / (1.f + __expf(-(xu + hu)));
      float nn = tanhf(xn + r * hn);
      hv[e] = u * hx + (1.f - u) * nn;
    }
    {
      bf16 h0b = (bf16)hv[0];
      bf16 h1b = (bf16)hv[1];
      bf16 l0b = (bf16)(hv[0] - (float)h0b);
      bf16 l1b = (bf16)(hv[1] - (float)h1b);
      u32 hp = (u32)__builtin_bit_cast(u16, h0b) | ((u32)__builtin_bit_cast(u16, h1b) << 16);
      u32 lp = (u32)__builtin_bit_cast(u16, l0b) | ((u32)__builtin_bit_cast(u16, l1b) << 16);
      bf16* wr = s1 ? h1ring + (t & 1) * 65536 : h0ring + (t & 3) * 65536;
      u32* whi = (u32*)wr + ((gb * 512 + cb) >> 1) + cp;
      __hip_atomic_store(whi, hp, __ATOMIC_RELAXED, __HIP_MEMORY_SCOPE_AGENT);
      __hip_atomic_store(whi + 16384, lp, __ATOMIC_RELAXED, __HIP_MEMORY_SCOPE_AGENT);
      if (s1) {
        *(float2*)&out[(size_t)gb * (NT * NH) + (size_t)t * NH + cb + 2 * cp] =
            make_float2(hv[0], hv[1]);
      }
    }
    __syncthreads();   // all waves' stores ack'd (vmcnt0 at barrier)
    if (tid == 0)
      __hip_atomic_store(myflag, (unsigned)(t + 1), __ATOMIC_RELAXED, __HIP_MEMORY_SCOPE_AGENT);
  }
}

// ---------------- host ----------------

extern "C" void kernel_launch(void* const* d_in, const int* in_sizes, int n_in,
                              void* d_out, int out_size, void* d_ws, size_t ws_size,
                              hipStream_t stream) {
  const float* x   = (const float*)d_in[0];
  const float* g   = (const float*)d_in[1];
  const float* Wx0 = (const float*)d_in[2];
  const float* bx0 = (const float*)d_in[3];
  const float* Wh0 = (const float*)d_in[4];
  const float* bh0 = (const float*)d_in[5];
  const float* Wm0 = (const float*)d_in[6];
  const float* bm0 = (const float*)d_in[7];
  const float* Wx1 = (const float*)d_in[8];
  const float* bx1 = (const float*)d_in[9];
  const float* Wh1 = (const float*)d_in[10];
  const float* bh1 = (const float*)d_in[11];
  const float* Wm1 = (const float*)d_in[12];
  const float* bm1 = (const float*)d_in[13];
  float* out = (float*)d_out;

  char* wp = (char*)d_ws;
  auto alloc = [&](size_t bytes) -> char* {
    char* p = wp;
    wp += (bytes + 255) & ~(size_t)255;
    return p;
  };
  bf16* x_hi   = (bf16*)alloc((size_t)NB * NT * NIN * 2);
  bf16* x_lo   = (bf16*)alloc((size_t)NB * NT * NIN * 2);
  bf16* Wx0H   = (bf16*)alloc(1536 * 256 * 2);
  bf16* Wx0L   = (bf16*)alloc(1536 * 256 * 2);
  bf16* Wx1H   = (bf16*)alloc(1536 * 512 * 2);
  bf16* Wx1L   = (bf16*)alloc(1536 * 512 * 2);
  bf16* Wh0H   = (bf16*)alloc(1536 * 512 * 2);
  bf16* Wh0L   = (bf16*)alloc(1536 * 512 * 2);
  bf16* Wh1H   = (bf16*)alloc(1536 * 512 * 2);
  bf16* Wh1L   = (bf16*)alloc(1536 * 512 * 2);
  bf16* Wm0hH  = (bf16*)alloc(512 * 512 * 2);
  bf16* Wm0hL  = (bf16*)alloc(512 * 512 * 2);
  bf16* Wm0tH  = (bf16*)alloc(512 * 512 * 2);
  bf16* Wm0tL  = (bf16*)alloc(512 * 512 * 2);
  bf16* Wg0H   = (bf16*)alloc(512 * 512 * 2);
  bf16* Wg0L   = (bf16*)alloc(512 * 512 * 2);
  bf16* Wm1hH  = (bf16*)alloc(512 * 512 * 2);
  bf16* Wm1hL  = (bf16*)alloc(512 * 512 * 2);
  bf16* Wm1tH  = (bf16*)alloc(512 * 512 * 2);
  bf16* Wm1tL  = (bf16*)alloc(512 * 512 * 2);
  bf16* Wg1H   = (bf16*)alloc(512 * 512 * 2);
  bf16* Wg1L   = (bf16*)alloc(512 * 512 * 2);
  bf16* gH     = (bf16*)alloc(64 * 512 * 2);
  bf16* gL     = (bf16*)alloc(64 * 512 * 2);
  float* gm0f  = (float*)alloc(64 * 512 * 4);
  float* gm1f  = (float*)alloc(64 * 512 * 4);
  bf16* gm0H   = (bf16*)alloc(64 * 512 * 2);
  bf16* gm0L   = (bf16*)alloc(64 * 512 * 2);
  bf16* gm1H   = (bf16*)alloc(64 * 512 * 2);
  bf16* gm1L   = (bf16*)alloc(64 * 512 * 2);
  float* ghb0f = (float*)alloc(64 * 1536 * 4);
  float* ghb1f = (float*)alloc(64 * 1536 * 4);
  bf16* Whc0H  = (bf16*)alloc(1536 * 512 * 2);
  bf16* Whc0L  = (bf16*)alloc(1536 * 512 * 2);
  bf16* Whc1H  = (bf16*)alloc(1536 * 512 * 2);
  bf16* Whc1L  = (bf16*)alloc(1536 * 512 * 2);
  bf16* h0ring = (bf16*)alloc(4 * 2 * 64 * 512 * 2);  // 524288 B
  bf16* h1ring = (bf16*)alloc(2 * 2 * 64 * 512 * 2);  // 262144 B
  u32* flags   = (u32*)alloc(512);
  u32* flags0 = flags;
  u32* flags1 = flags + 64;

  // conversions (hi/lo splits)
  k_cvt_hl<<<2048, 256, 0, stream>>>((const float4*)x, (bf16x4*)x_hi, (bf16x4*)x_lo,
                                     (NB * NT * NIN) / 4);
  k_cvt_hl<<<384, 256, 0, stream>>>((const float4*)Wx0, (bf16x4*)Wx0H, (bf16x4*)Wx0L,
                                    (1536 * 256) / 4);
  k_cvt_hl<<<768, 256, 0, stream>>>((const float4*)Wx1, (bf16x4*)Wx1H, (bf16x4*)Wx1L,
                                    (1536 * 512) / 4);
  k_cvt_hl<<<768, 256, 0, stream>>>((const float4*)Wh0, (bf16x4*)Wh0H, (bf16x4*)Wh0L,
                                    (1536 * 512) / 4);
  k_cvt_hl<<<768, 256, 0, stream>>>((const float4*)Wh1, (bf16x4*)Wh1H, (bf16x4*)Wh1L,
                                    (1536 * 512) / 4);
  k_cvt_hl<<<32, 256, 0, stream>>>((const float4*)g, (bf16x4*)gH, (bf16x4*)gL,
                                   (64 * 512) / 4);
  k_cvt_wm<<<1024, 256, 0, stream>>>(Wm0, Wm0hH, Wm0hL, Wm0tH, Wm0tL, Wg0H, Wg0L);
  k_cvt_wm<<<1024, 256, 0, stream>>>(Wm1, Wm1hH, Wm1hL, Wm1tH, Wm1tL, Wg1H, Wg1L);

  // gm = g @ Wm[:, :G]^T + bm  (f32 + hi/lo)
  k_gemm<<<dim3(8, 1), 256, 0, stream>>>(gH, gL, 512, Wg0H, Wg0L, 512, bm0,
                                         gm0f, gm0H, gm0L, 512, 512);
  k_gemm<<<dim3(8, 1), 256, 0, stream>>>(gH, gL, 512, Wg1H, Wg1L, 512, bm1,
                                         gm1f, gm1H, gm1L, 512, 512);
  // ghb = gm @ Wh^T + bh  (f32)
  k_gemm<<<dim3(24, 1), 256, 0, stream>>>(gm0H, gm0L, 512, Wh0H, Wh0L, 512, bh0,
                                          ghb0f, (bf16*)nullptr, (bf16*)nullptr, 1536, 512);
  k_gemm<<<dim3(24, 1), 256, 0, stream>>>(gm1H, gm1L, 512, Wh1H, Wh1L, 512, bh1,
                                          ghb1f, (bf16*)nullptr, (bf16*)nullptr, 1536, 512);
  // Whc = Wh @ Wmh  (hi/lo); B[n][k] = Wmh[k][n] = WmhT
  k_gemm<<<dim3(8, 24), 256, 0, stream>>>(Wh0H, Wh0L, 512, Wm0tH, Wm0tL, 512,
                                          (const float*)nullptr, (float*)nullptr,
                                          Whc0H, Whc0L, 512, 512);
  k_gemm<<<dim3(8, 24), 256, 0, stream>>>(Wh1H, Wh1L, 512, Wm1tH, Wm1tL, 512,
                                          (const float*)nullptr, (float*)nullptr,
                                          Whc1H, Whc1L, 512, 512);

  // zero rings + flags (contiguous in ws)
  hipMemsetAsync(h0ring, 0, 524288 + 262144 + 512, stream);

  k_scan<<<128, 256, 0, stream>>>(
      x_hi, x_lo,
      Wm0hH, Wm0hL, Whc0H, Whc0L, Wx0H, Wx0L,
      Wm1hH, Wm1hL, Whc1H, Whc1L, Wx1H, Wx1L,
      gm0f, ghb0f, bx0, gm1f, ghb1f, bx1,
      h0ring, h1ring, flags0, flags1, out);
}

// Round 6
// 5526.802 us; speedup vs baseline: 1.4603x; 1.4603x over previous
//
#include <hip/hip_runtime.h>
#include <hip/hip_bf16.h>
#include <cstdint>
#include <cstddef>

typedef __bf16 bf16;
typedef bf16 bf16x8 __attribute__((ext_vector_type(8)));
typedef bf16 bf16x4 __attribute__((ext_vector_type(4)));
typedef float f32x16 __attribute__((ext_vector_type(16)));
typedef float f32x4 __attribute__((ext_vector_type(4)));
typedef unsigned int u32;
typedef unsigned short u16;
typedef unsigned long long u64;

#define NB 64
#define NT 512
#define NIN 256
#define NH 512
#define FLAG_STRIDE 32         // u32 words: one flag per 128B line
#define SLOT_ELEMS 65536       // one ring slot: [hi|lo][64][512] bf16
#define DEEP_RING_BYTES ((size_t)(NT + 1) * SLOT_ELEMS * 2)   // 513 slots

// ---------------- setup kernels ----------------

// f32 -> (hi, lo) bf16 split, vectorized x4
__global__ __launch_bounds__(256) void k_cvt_hl(const float4* __restrict__ src,
                                                bf16x4* __restrict__ dhi,
                                                bf16x4* __restrict__ dlo, int n4) {
  int i = blockIdx.x * 256 + threadIdx.x;
  int st = gridDim.x * 256;
  for (; i < n4; i += st) {
    float4 f = src[i];
    bf16x4 h, l;
    h[0] = (bf16)f.x; l[0] = (bf16)(f.x - (float)h[0]);
    h[1] = (bf16)f.y; l[1] = (bf16)(f.y - (float)h[1]);
    h[2] = (bf16)f.z; l[2] = (bf16)(f.z - (float)h[2]);
    h[3] = (bf16)f.w; l[3] = (bf16)(f.w - (float)h[3]);
    dhi[i] = h; dlo[i] = l;
  }
}

// Wm (512 x 1024) -> Wmh(hi/lo) [o][k]=Wm[o][512+k], WmhT(hi/lo) [j][k]=Wm[k][512+j],
//                    Wg(hi/lo)  [o][k]=Wm[o][k]   (all 512x512)
__global__ __launch_bounds__(256) void k_cvt_wm(const float* __restrict__ Wm,
                                                bf16* __restrict__ WmhH, bf16* __restrict__ WmhL,
                                                bf16* __restrict__ WmhTH, bf16* __restrict__ WmhTL,
                                                bf16* __restrict__ WgH, bf16* __restrict__ WgL) {
  int i = blockIdx.x * 256 + threadIdx.x;  // 262144 total
  int a = i >> 9, b = i & 511;
  float w1 = Wm[a * 1024 + 512 + b];
  float w2 = Wm[a * 1024 + b];
  float w3 = Wm[b * 1024 + 512 + a];
  bf16 h;
  h = (bf16)w1; WmhH[i] = h;  WmhL[i]  = (bf16)(w1 - (float)h);
  h = (bf16)w2; WgH[i] = h;   WgL[i]   = (bf16)(w2 - (float)h);
  h = (bf16)w3; WmhTH[i] = h; WmhTL[i] = (bf16)(w3 - (float)h);
}

// C[m][n] = sum_k A[m][k]*B[n][k] (+bias[n]); hi/lo 3-product; f32 and/or hi/lo bf16 out.
__global__ __launch_bounds__(256) void k_gemm(const bf16* __restrict__ Ahi, const bf16* __restrict__ Alo,
                                              int lda,
                                              const bf16* __restrict__ Bhi, const bf16* __restrict__ Blo,
                                              int ldb,
                                              const float* __restrict__ bias,
                                              float* __restrict__ outf,
                                              bf16* __restrict__ outhi, bf16* __restrict__ outlo,
                                              int ldc, int K) {
  int tid = threadIdx.x;
  int wave = tid >> 6, lane = tid & 63;
  int wm = wave >> 1, wn = wave & 1;
  int row0 = blockIdx.y * 64 + wm * 32 + (lane & 31);
  int col0 = blockIdx.x * 64 + wn * 32 + (lane & 31);
  int kk = (lane >> 5) * 8;
  const bf16* ah = Ahi + (size_t)row0 * lda + kk;
  const bf16* al = Alo + (size_t)row0 * lda + kk;
  const bf16* bh = Bhi + (size_t)col0 * ldb + kk;
  const bf16* bl = Blo + (size_t)col0 * ldb + kk;
  f32x16 acc;
#pragma unroll
  for (int i = 0; i < 16; ++i) acc[i] = 0.f;
  for (int ks = 0; ks < K / 16; ++ks) {
    bf16x8 a0 = *(const bf16x8*)(ah + ks * 16);
    bf16x8 a1 = *(const bf16x8*)(al + ks * 16);
    bf16x8 b0 = *(const bf16x8*)(bh + ks * 16);
    bf16x8 b1 = *(const bf16x8*)(bl + ks * 16);
    acc = __builtin_amdgcn_mfma_f32_32x32x16_bf16(a0, b0, acc, 0, 0, 0);
    acc = __builtin_amdgcn_mfma_f32_32x32x16_bf16(a1, b0, acc, 0, 0, 0);
    acc = __builtin_amdgcn_mfma_f32_32x32x16_bf16(a0, b1, acc, 0, 0, 0);
  }
  int col = blockIdx.x * 64 + wn * 32 + (lane & 31);
  int rowb = blockIdx.y * 64 + wm * 32;
  float bv = bias ? bias[col] : 0.f;
#pragma unroll
  for (int j = 0; j < 16; ++j) {
    int row = rowb + (j & 3) + 8 * (j >> 2) + 4 * (lane >> 5);
    float v = acc[j] + bv;
    size_t o = (size_t)row * ldc + col;
    if (outf) outf[o] = v;
    if (outhi) { bf16 h = (bf16)v; outhi[o] = h; outlo[o] = (bf16)(v - (float)h); }
  }
}

// ---------------- main scan kernel ----------------

// poll 64 line-padded flags, one per lane, until all >= tgt
__device__ __forceinline__ void wave_poll(const u32* f, int lane, unsigned tgt) {
  const u32* p = f + lane * FLAG_STRIDE;
  for (;;) {
    unsigned v = __hip_atomic_load(p, __ATOMIC_RELAXED, __HIP_MEMORY_SCOPE_AGENT);
    if (__all((int)(v >= tgt))) break;
    __builtin_amdgcn_s_sleep(2);
  }
  asm volatile("" ::: "memory");   // no load may be hoisted above the poll
}

// L2-bypassing 16B ring load (two agent-scope relaxed b64 loads)
union B16U { u64 q[2]; bf16x8 v; };
__device__ __forceinline__ bf16x8 ld_bypass(const bf16* p) {
  const u64* q = (const u64*)p;
  B16U u;
  u.q[0] = __hip_atomic_load(q,     __ATOMIC_RELAXED, __HIP_MEMORY_SCOPE_AGENT);
  u.q[1] = __hip_atomic_load(q + 1, __ATOMIC_RELAXED, __HIP_MEMORY_SCOPE_AGENT);
  return u.v;
}

template<bool DEEP>
__device__ __forceinline__ bf16x8 ld_ring(const bf16* p) {
  if constexpr (DEEP) return *(const bf16x8*)p;   // write-once address: cached load is fresh
  else return ld_bypass(p);
}

__device__ __forceinline__ float fast_sigmoid(float z) {
  return 1.f / (1.f + __expf(-z));
}
__device__ __forceinline__ float fast_tanh(float z) {
  z = fminf(fmaxf(z, -20.f), 20.f);
  float e2 = __expf(-2.f * z);
  return (1.f - e2) / (1.f + e2);
}

// grid 128: blocks 0..63 = stage 0 (layer 0), 64..127 = stage 1 (layer 1, one step behind).
// Each WG owns 8 gate-columns. Weights (hi/lo) live in registers for the whole scan.
// DEEP mode: rings have one slot per step (write-once addresses) -> consumers use plain
// cached loads (L2 filters the 16-WG broadcast per XCD); no backpressure; no pre-barrier.
// Shallow mode: 4/2-slot rings, L2-bypassing atomic loads (round-2-proven flow).
template<bool DEEP>
__global__ __launch_bounds__(256, 1) void k_scan(
    const bf16* __restrict__ xhi, const bf16* __restrict__ xlo,
    const bf16* __restrict__ Wm0hH, const bf16* __restrict__ Wm0hL,
    const bf16* __restrict__ Whc0H, const bf16* __restrict__ Whc0L,
    const bf16* __restrict__ Wx0H, const bf16* __restrict__ Wx0L,
    const bf16* __restrict__ Wm1hH, const bf16* __restrict__ Wm1hL,
    const bf16* __restrict__ Whc1H, const bf16* __restrict__ Whc1L,
    const bf16* __restrict__ Wx1H, const bf16* __restrict__ Wx1L,
    const float* __restrict__ gm0f, const float* __restrict__ ghb0f, const float* __restrict__ bx0,
    const float* __restrict__ gm1f, const float* __restrict__ ghb1f, const float* __restrict__ bx1,
    bf16* __restrict__ h0ring,
    bf16* __restrict__ h1ring,
    u32* __restrict__ flags0, u32* __restrict__ flags1,
    float* __restrict__ out) {
  __shared__ __align__(16) float RedH[32][68];
  __shared__ __align__(16) float RedX[32][68];
  __shared__ float gmL[64][8];
  __shared__ float ghbL[3][64][8];
  __shared__ float bxL[24];

  const int tid = threadIdx.x;
  const int wave = tid >> 6, lane = tid & 63;
  const bool s1 = blockIdx.x >= 64;
  const int w = s1 ? (int)blockIdx.x - 64 : (int)blockIdx.x;
  const int cb = w * 8;

  const float* gmf = s1 ? gm1f : gm0f;
  const float* ghbf = s1 ? ghb1f : ghb0f;
  const float* bxv = s1 ? bx1 : bx0;

  for (int i = tid; i < 512; i += 256) gmL[i >> 3][i & 7] = gmf[(i >> 3) * 512 + cb + (i & 7)];
  for (int i = tid; i < 1536; i += 256) {
    int g = i / 512, j = i - g * 512;
    ghbL[g][j >> 3][j & 7] = ghbf[(j >> 3) * 1536 + g * 512 + cb + (j & 7)];
  }
  if (tid < 24) bxL[tid] = bxv[(tid >> 3) * 512 + cb + (tid & 7)];
  // gmL/ghbL/bxL are first read after the mid-step barrier, so no barrier needed here.

  const bool isH = wave < 2;   // waves 0,1: h-recurrence matmul; 2,3: x-path matmul
  const int mt = wave & 1;     // M-tile (batch rows 32*mt..)
  const int n = lane & 31;     // B column (packed gate row)
  const int kk8 = (lane >> 5) * 8;
  const int arow = mt * 32 + n;

  // ---- one-time: B fragments (hi+lo) into registers ----
  bf16x8 Bhi[32], Blo[32];
  bf16x8 zz;
#pragma unroll
  for (int i = 0; i < 8; ++i) zz[i] = (bf16)0.f;

  if (isH) {
    const bf16 *WH, *WL;
    size_t roff;
    if (n < 8) {
      WH = s1 ? Wm1hH : Wm0hH; WL = s1 ? Wm1hL : Wm0hL;
      roff = (size_t)(cb + n) * 512;
    } else {
      WH = s1 ? Whc1H : Whc0H; WL = s1 ? Whc1L : Whc0L;
      roff = (size_t)(((n >> 3) - 1) * 512 + cb + (n & 7)) * 512;
    }
#pragma unroll
    for (int ks = 0; ks < 32; ++ks) {
      Bhi[ks] = *(const bf16x8*)(WH + roff + ks * 16 + kk8);
      Blo[ks] = *(const bf16x8*)(WL + roff + ks * 16 + kk8);
    }
  } else if (s1) {
    size_t roff = n < 24 ? (size_t)((n >> 3) * 512 + cb + (n & 7)) * 512 : 0;
    bool val = n < 24;
#pragma unroll
    for (int ks = 0; ks < 32; ++ks) {
      bf16x8 bh = *(const bf16x8*)(Wx1H + roff + ks * 16 + kk8);
      bf16x8 bl = *(const bf16x8*)(Wx1L + roff + ks * 16 + kk8);
      Bhi[ks] = val ? bh : zz;
      Blo[ks] = val ? bl : zz;
    }
  } else {
    size_t roff = n < 24 ? (size_t)((n >> 3) * 512 + cb + (n & 7)) * 256 : 0;
    bool val = n < 24;
#pragma unroll
    for (int ks = 0; ks < 16; ++ks) {
      bf16x8 bh = *(const bf16x8*)(Wx0H + roff + ks * 16 + kk8);
      bf16x8 bl = *(const bf16x8*)(Wx0L + roff + ks * 16 + kk8);
      Bhi[ks] = val ? bh : zz;
      Blo[ks] = val ? bl : zz;
    }
  }

  const u32* selfF = s1 ? flags1 : flags0;
  const u32* othF  = s1 ? flags0 : flags1;
  u32* myflag = (s1 ? flags1 : flags0) + w * FLAG_STRIDE;

  const int gb = tid >> 2, cp = tid & 3;  // gate phase: thread -> (batch gb, col pair cp)

#pragma unroll 1
  for (int t = 0; t < NT; ++t) {
    if constexpr (DEEP) {
      // each wave polls exactly the conditions ITS loads require; no pre-barrier
      if (isH) {
        if (t > 0) wave_poll(selfF, lane, (unsigned)t);            // peers finished t-1
      } else if (s1) {
        wave_poll(othF, lane, (unsigned)(t + 1));                  // h0[t] ready
      }  // stage-0 x-waves: no dependency
    } else {
      if (wave == 0) {
        if (t > 0) wave_poll(selfF, lane, (unsigned)t);
      } else if (wave == 1) {
        if (s1) wave_poll(othF, lane, (unsigned)(t + 1));
        else if (t >= 4) wave_poll(othF, lane, (unsigned)(t - 3)); // ring backpressure
      }
      __syncthreads();
    }

    f32x16 acc;
#pragma unroll
    for (int i = 0; i < 16; ++i) acc[i] = 0.f;

    if (isH || s1) {
      // A = h-state (hi plane, lo plane at +32768), K = 512
      const bf16* Ah;
      if constexpr (DEEP) {
        Ah = (isH ? (s1 ? h1ring : h0ring) + (size_t)t * SLOT_ELEMS      // h[t-1] at slot t
                  : h0ring + (size_t)(t + 1) * SLOT_ELEMS)               // h0[t] at slot t+1
             + arow * 512 + kk8;
      } else {
        if (isH)
          Ah = (s1 ? h1ring + ((t + 1) & 1) * SLOT_ELEMS
                   : h0ring + ((t + 3) & 3) * SLOT_ELEMS) + arow * 512 + kk8;
        else
          Ah = h0ring + (t & 3) * SLOT_ELEMS + arow * 512 + kk8;
      }
#pragma unroll
      for (int ks = 0; ks < 32; ++ks) {
        bf16x8 a0 = ld_ring<DEEP>(Ah + ks * 16);
        bf16x8 a1 = ld_ring<DEEP>(Ah + 32768 + ks * 16);
        acc = __builtin_amdgcn_mfma_f32_32x32x16_bf16(a0, Bhi[ks], acc, 0, 0, 0);
        acc = __builtin_amdgcn_mfma_f32_32x32x16_bf16(a1, Bhi[ks], acc, 0, 0, 0);
        acc = __builtin_amdgcn_mfma_f32_32x32x16_bf16(a0, Blo[ks], acc, 0, 0, 0);
      }
    } else {
      // stage-0 X: A = x[:, t, :] (hi/lo arrays), K = 256 — regular cached loads
      const bf16* Ah = xhi + (size_t)arow * (NT * NIN) + t * NIN + kk8;
      const bf16* Al = xlo + (size_t)arow * (NT * NIN) + t * NIN + kk8;
#pragma unroll
      for (int ks = 0; ks < 16; ++ks) {
        bf16x8 a0 = *(const bf16x8*)(Ah + ks * 16);
        bf16x8 a1 = *(const bf16x8*)(Al + ks * 16);
        acc = __builtin_amdgcn_mfma_f32_32x32x16_bf16(a0, Bhi[ks], acc, 0, 0, 0);
        acc = __builtin_amdgcn_mfma_f32_32x32x16_bf16(a1, Bhi[ks], acc, 0, 0, 0);
        acc = __builtin_amdgcn_mfma_f32_32x32x16_bf16(a0, Blo[ks], acc, 0, 0, 0);
      }
    }

    {  // C fragments -> LDS transpose buffer: Red[packed_col][batch_row]
      float (*Red)[68] = isH ? RedH : RedX;
#pragma unroll
      for (int rg = 0; rg < 4; ++rg) {
        f32x4 v;
        v[0] = acc[4 * rg]; v[1] = acc[4 * rg + 1];
        v[2] = acc[4 * rg + 2]; v[3] = acc[4 * rg + 3];
        *(f32x4*)&Red[n][mt * 32 + rg * 8 + ((lane >> 5) << 2)] = v;
      }
    }
    __syncthreads();

    // gate phase: thread handles (gb, c=2cp) and (gb, c=2cp+1)
    float hv[2];
#pragma unroll
    for (int e = 0; e < 2; ++e) {
      int c = 2 * cp + e;
      float hx = gmL[gb][c] + RedH[c][gb];
      float hr = ghbL[0][gb][c] + RedH[8 + c][gb];
      float hu = ghbL[1][gb][c] + RedH[16 + c][gb];
      float hn = ghbL[2][gb][c] + RedH[24 + c][gb];
      float xr = bxL[c] + RedX[c][gb];
      float xu = bxL[8 + c] + RedX[8 + c][gb];
      float xn = bxL[16 + c] + RedX[16 + c][gb];
      float r = fast_sigmoid(xr + hr);
      float u = fast_sigmoid(xu + hu);
      float nn = fast_tanh(xn + r * hn);
      hv[e] = u * hx + (1.f - u) * nn;
    }
    {
      bf16 h0b = (bf16)hv[0];
      bf16 h1b = (bf16)hv[1];
      bf16 l0b = (bf16)(hv[0] - (float)h0b);
      bf16 l1b = (bf16)(hv[1] - (float)h1b);
      u32 hp = (u32)__builtin_bit_cast(u16, h0b) | ((u32)__builtin_bit_cast(u16, h1b) << 16);
      u32 lp = (u32)__builtin_bit_cast(u16, l0b) | ((u32)__builtin_bit_cast(u16, l1b) << 16);
      bf16* wr;
      if constexpr (DEEP)
        wr = (s1 ? h1ring : h0ring) + (size_t)(t + 1) * SLOT_ELEMS;   // h[t] at slot t+1
      else
        wr = s1 ? h1ring + (t & 1) * SLOT_ELEMS : h0ring + (t & 3) * SLOT_ELEMS;
      u32* whi = (u32*)wr + ((gb * 512 + cb) >> 1) + cp;
      // write-through (agent scope): visible at L3 before the flag below
      __hip_atomic_store(whi, hp, __ATOMIC_RELAXED, __HIP_MEMORY_SCOPE_AGENT);
      __hip_atomic_store(whi + 16384, lp, __ATOMIC_RELAXED, __HIP_MEMORY_SCOPE_AGENT);
    }
    __syncthreads();   // vmcnt(0) drain: all waves' ring stores ack'd before the flag
    if (tid == 0)
      __hip_atomic_store(myflag, (unsigned)(t + 1), __ATOMIC_RELAXED, __HIP_MEMORY_SCOPE_AGENT);
    if (s1) {          // out store off the critical path (regular cached store)
      *(float2*)&out[(size_t)gb * (NT * NH) + (size_t)t * NH + cb + 2 * cp] =
          make_float2(hv[0], hv[1]);
    }
  }
}

// ---------------- host ----------------

extern "C" void kernel_launch(void* const* d_in, const int* in_sizes, int n_in,
                              void* d_out, int out_size, void* d_ws, size_t ws_size,
                              hipStream_t stream) {
  const float* x   = (const float*)d_in[0];
  const float* g   = (const float*)d_in[1];
  const float* Wx0 = (const float*)d_in[2];
  const float* bx0 = (const float*)d_in[3];
  const float* Wh0 = (const float*)d_in[4];
  const float* bh0 = (const float*)d_in[5];
  const float* Wm0 = (const float*)d_in[6];
  const float* bm0 = (const float*)d_in[7];
  const float* Wx1 = (const float*)d_in[8];
  const float* bx1 = (const float*)d_in[9];
  const float* Wh1 = (const float*)d_in[10];
  const float* bh1 = (const float*)d_in[11];
  const float* Wm1 = (const float*)d_in[12];
  const float* bm1 = (const float*)d_in[13];
  float* out = (float*)d_out;

  char* wp = (char*)d_ws;
  auto alloc = [&](size_t bytes) -> char* {
    char* p = wp;
    wp += (bytes + 255) & ~(size_t)255;
    return p;
  };
  bf16* x_hi   = (bf16*)alloc((size_t)NB * NT * NIN * 2);
  bf16* x_lo   = (bf16*)alloc((size_t)NB * NT * NIN * 2);
  bf16* Wx0H   = (bf16*)alloc(1536 * 256 * 2);
  bf16* Wx0L   = (bf16*)alloc(1536 * 256 * 2);
  bf16* Wx1H   = (bf16*)alloc(1536 * 512 * 2);
  bf16* Wx1L   = (bf16*)alloc(1536 * 512 * 2);
  bf16* Wh0H   = (bf16*)alloc(1536 * 512 * 2);
  bf16* Wh0L   = (bf16*)alloc(1536 * 512 * 2);
  bf16* Wh1H   = (bf16*)alloc(1536 * 512 * 2);
  bf16* Wh1L   = (bf16*)alloc(1536 * 512 * 2);
  bf16* Wm0hH  = (bf16*)alloc(512 * 512 * 2);
  bf16* Wm0hL  = (bf16*)alloc(512 * 512 * 2);
  bf16* Wm0tH  = (bf16*)alloc(512 * 512 * 2);
  bf16* Wm0tL  = (bf16*)alloc(512 * 512 * 2);
  bf16* Wg0H   = (bf16*)alloc(512 * 512 * 2);
  bf16* Wg0L   = (bf16*)alloc(512 * 512 * 2);
  bf16* Wm1hH  = (bf16*)alloc(512 * 512 * 2);
  bf16* Wm1hL  = (bf16*)alloc(512 * 512 * 2);
  bf16* Wm1tH  = (bf16*)alloc(512 * 512 * 2);
  bf16* Wm1tL  = (bf16*)alloc(512 * 512 * 2);
  bf16* Wg1H   = (bf16*)alloc(512 * 512 * 2);
  bf16* Wg1L   = (bf16*)alloc(512 * 512 * 2);
  bf16* gH     = (bf16*)alloc(64 * 512 * 2);
  bf16* gL     = (bf16*)alloc(64 * 512 * 2);
  float* gm0f  = (float*)alloc(64 * 512 * 4);
  float* gm1f  = (float*)alloc(64 * 512 * 4);
  bf16* gm0H   = (bf16*)alloc(64 * 512 * 2);
  bf16* gm0L   = (bf16*)alloc(64 * 512 * 2);
  bf16* gm1H   = (bf16*)alloc(64 * 512 * 2);
  bf16* gm1L   = (bf16*)alloc(64 * 512 * 2);
  float* ghb0f = (float*)alloc(64 * 1536 * 4);
  float* ghb1f = (float*)alloc(64 * 1536 * 4);
  bf16* Whc0H  = (bf16*)alloc(1536 * 512 * 2);
  bf16* Whc0L  = (bf16*)alloc(1536 * 512 * 2);
  bf16* Whc1H  = (bf16*)alloc(1536 * 512 * 2);
  bf16* Whc1L  = (bf16*)alloc(1536 * 512 * 2);
  bf16* h0ring = (bf16*)alloc(4 * (size_t)SLOT_ELEMS * 2);   // 524288 B (shallow)
  bf16* h1ring = (bf16*)alloc(2 * (size_t)SLOT_ELEMS * 2);   // 262144 B (shallow)
  u32* flags   = (u32*)alloc(2 * 64 * FLAG_STRIDE * 4);      // 32768 B, line-padded
  u32* flags0 = flags;
  u32* flags1 = flags + 64 * FLAG_STRIDE;

  // deep rings (write-once slots) if the workspace is big enough
  size_t base_end = (size_t)(wp - (char*)d_ws);
  bool deep = (base_end + 2 * DEEP_RING_BYTES) <= ws_size;
  bf16 *h0deep = nullptr, *h1deep = nullptr;
  if (deep) {
    h0deep = (bf16*)alloc(DEEP_RING_BYTES);
    h1deep = (bf16*)alloc(DEEP_RING_BYTES);
  }

  // conversions (hi/lo splits)
  k_cvt_hl<<<2048, 256, 0, stream>>>((const float4*)x, (bf16x4*)x_hi, (bf16x4*)x_lo,
                                     (NB * NT * NIN) / 4);
  k_cvt_hl<<<384, 256, 0, stream>>>((const float4*)Wx0, (bf16x4*)Wx0H, (bf16x4*)Wx0L,
                                    (1536 * 256) / 4);
  k_cvt_hl<<<768, 256, 0, stream>>>((const float4*)Wx1, (bf16x4*)Wx1H, (bf16x4*)Wx1L,
                                    (1536 * 512) / 4);
  k_cvt_hl<<<768, 256, 0, stream>>>((const float4*)Wh0, (bf16x4*)Wh0H, (bf16x4*)Wh0L,
                                    (1536 * 512) / 4);
  k_cvt_hl<<<768, 256, 0, stream>>>((const float4*)Wh1, (bf16x4*)Wh1H, (bf16x4*)Wh1L,
                                    (1536 * 512) / 4);
  k_cvt_hl<<<32, 256, 0, stream>>>((const float4*)g, (bf16x4*)gH, (bf16x4*)gL,
                                   (64 * 512) / 4);
  k_cvt_wm<<<1024, 256, 0, stream>>>(Wm0, Wm0hH, Wm0hL, Wm0tH, Wm0tL, Wg0H, Wg0L);
  k_cvt_wm<<<1024, 256, 0, stream>>>(Wm1, Wm1hH, Wm1hL, Wm1tH, Wm1tL, Wg1H, Wg1L);

  // gm = g @ Wm[:, :G]^T + bm  (f32 + hi/lo)
  k_gemm<<<dim3(8, 1), 256, 0, stream>>>(gH, gL, 512, Wg0H, Wg0L, 512, bm0,
                                         gm0f, gm0H, gm0L, 512, 512);
  k_gemm<<<dim3(8, 1), 256, 0, stream>>>(gH, gL, 512, Wg1H, Wg1L, 512, bm1,
                                         gm1f, gm1H, gm1L, 512, 512);
  // ghb = gm @ Wh^T + bh  (f32)
  k_gemm<<<dim3(24, 1), 256, 0, stream>>>(gm0H, gm0L, 512, Wh0H, Wh0L, 512, bh0,
                                          ghb0f, (bf16*)nullptr, (bf16*)nullptr, 1536, 512);
  k_gemm<<<dim3(24, 1), 256, 0, stream>>>(gm1H, gm1L, 512, Wh1H, Wh1L, 512, bh1,
                                          ghb1f, (bf16*)nullptr, (bf16*)nullptr, 1536, 512);
  // Whc = Wh @ Wmh  (hi/lo); B[n][k] = Wmh[k][n] = WmhT
  k_gemm<<<dim3(8, 24), 256, 0, stream>>>(Wh0H, Wh0L, 512, Wm0tH, Wm0tL, 512,
                                          (const float*)nullptr, (float*)nullptr,
                                          Whc0H, Whc0L, 512, 512);
  k_gemm<<<dim3(8, 24), 256, 0, stream>>>(Wh1H, Wh1L, 512, Wm1tH, Wm1tL, 512,
                                          (const float*)nullptr, (float*)nullptr,
                                          Whc1H, Whc1L, 512, 512);

  if (deep) {
    // zero flags + slot 0 of each deep ring (h[-1] = 0)
    hipMemsetAsync(flags, 0, 2 * 64 * FLAG_STRIDE * 4, stream);
    hipMemsetAsync(h0deep, 0, SLOT_ELEMS * 2, stream);
    hipMemsetAsync(h1deep, 0, SLOT_ELEMS * 2, stream);
    k_scan<true><<<128, 256, 0, stream>>>(
        x_hi, x_lo,
        Wm0hH, Wm0hL, Whc0H, Whc0L, Wx0H, Wx0L,
        Wm1hH, Wm1hL, Whc1H, Whc1L, Wx1H, Wx1L,
        gm0f, ghb0f, bx0, gm1f, ghb1f, bx1,
        h0deep, h1deep, flags0, flags1, out);
  } else {
    // zero shallow rings + flags (contiguous in ws)
    hipMemsetAsync(h0ring, 0, 524288 + 262144 + 32768, stream);
    k_scan<false><<<128, 256, 0, stream>>>(
        x_hi, x_lo,
        Wm0hH, Wm0hL, Whc0H, Whc0L, Wx0H, Wx0L,
        Wm1hH, Wm1hL, Whc1H, Whc1L, Wx1H, Wx1L,
        gm0f, ghb0f, bx0, gm1f, ghb1f, bx1,
        h0ring, h1ring, flags0, flags1, out);
  }
}

// Round 7
// 5402.486 us; speedup vs baseline: 1.4939x; 1.0230x over previous
//
#include <hip/hip_runtime.h>
#include <hip/hip_bf16.h>
#include <cstdint>
#include <cstddef>

typedef __bf16 bf16;
typedef bf16 bf16x8 __attribute__((ext_vector_type(8)));
typedef bf16 bf16x4 __attribute__((ext_vector_type(4)));
typedef float f32x16 __attribute__((ext_vector_type(16)));
typedef float f32x4 __attribute__((ext_vector_type(4)));
typedef unsigned int u32;
typedef unsigned short u16;
typedef unsigned long long u64;

#define NB 64
#define NT 512
#define NIN 256
#define NH 512
#define FLAG_STRIDE 32         // u32 words: one flag per 128B line
#define N_RELAY0 32            // relay lines for stage-0 progress (P0)
#define N_RELAY1 16            // relay lines for stage-1 progress (P1)
#define SLOT_ELEMS 65536       // one ring slot: [hi|lo][64][512] bf16
#define DEEP_RING_BYTES ((size_t)(NT + 1) * SLOT_ELEMS * 2)   // 513 slots

// ---------------- setup kernels ----------------

// f32 -> (hi, lo) bf16 split, vectorized x4
__global__ __launch_bounds__(256) void k_cvt_hl(const float4* __restrict__ src,
                                                bf16x4* __restrict__ dhi,
                                                bf16x4* __restrict__ dlo, int n4) {
  int i = blockIdx.x * 256 + threadIdx.x;
  int st = gridDim.x * 256;
  for (; i < n4; i += st) {
    float4 f = src[i];
    bf16x4 h, l;
    h[0] = (bf16)f.x; l[0] = (bf16)(f.x - (float)h[0]);
    h[1] = (bf16)f.y; l[1] = (bf16)(f.y - (float)h[1]);
    h[2] = (bf16)f.z; l[2] = (bf16)(f.z - (float)h[2]);
    h[3] = (bf16)f.w; l[3] = (bf16)(f.w - (float)h[3]);
    dhi[i] = h; dlo[i] = l;
  }
}

// Wm (512 x 1024) -> Wmh(hi/lo) [o][k]=Wm[o][512+k], WmhT(hi/lo) [j][k]=Wm[k][512+j],
//                    Wg(hi/lo)  [o][k]=Wm[o][k]   (all 512x512)
__global__ __launch_bounds__(256) void k_cvt_wm(const float* __restrict__ Wm,
                                                bf16* __restrict__ WmhH, bf16* __restrict__ WmhL,
                                                bf16* __restrict__ WmhTH, bf16* __restrict__ WmhTL,
                                                bf16* __restrict__ WgH, bf16* __restrict__ WgL) {
  int i = blockIdx.x * 256 + threadIdx.x;  // 262144 total
  int a = i >> 9, b = i & 511;
  float w1 = Wm[a * 1024 + 512 + b];
  float w2 = Wm[a * 1024 + b];
  float w3 = Wm[b * 1024 + 512 + a];
  bf16 h;
  h = (bf16)w1; WmhH[i] = h;  WmhL[i]  = (bf16)(w1 - (float)h);
  h = (bf16)w2; WgH[i] = h;   WgL[i]   = (bf16)(w2 - (float)h);
  h = (bf16)w3; WmhTH[i] = h; WmhTL[i] = (bf16)(w3 - (float)h);
}

// C[m][n] = sum_k A[m][k]*B[n][k] (+bias[n]); hi/lo 3-product; f32 and/or hi/lo bf16 out.
__global__ __launch_bounds__(256) void k_gemm(const bf16* __restrict__ Ahi, const bf16* __restrict__ Alo,
                                              int lda,
                                              const bf16* __restrict__ Bhi, const bf16* __restrict__ Blo,
                                              int ldb,
                                              const float* __restrict__ bias,
                                              float* __restrict__ outf,
                                              bf16* __restrict__ outhi, bf16* __restrict__ outlo,
                                              int ldc, int K) {
  int tid = threadIdx.x;
  int wave = tid >> 6, lane = tid & 63;
  int wm = wave >> 1, wn = wave & 1;
  int row0 = blockIdx.y * 64 + wm * 32 + (lane & 31);
  int col0 = blockIdx.x * 64 + wn * 32 + (lane & 31);
  int kk = (lane >> 5) * 8;
  const bf16* ah = Ahi + (size_t)row0 * lda + kk;
  const bf16* al = Alo + (size_t)row0 * lda + kk;
  const bf16* bh = Bhi + (size_t)col0 * ldb + kk;
  const bf16* bl = Blo + (size_t)col0 * ldb + kk;
  f32x16 acc;
#pragma unroll
  for (int i = 0; i < 16; ++i) acc[i] = 0.f;
  for (int ks = 0; ks < K / 16; ++ks) {
    bf16x8 a0 = *(const bf16x8*)(ah + ks * 16);
    bf16x8 a1 = *(const bf16x8*)(al + ks * 16);
    bf16x8 b0 = *(const bf16x8*)(bh + ks * 16);
    bf16x8 b1 = *(const bf16x8*)(bl + ks * 16);
    acc = __builtin_amdgcn_mfma_f32_32x32x16_bf16(a0, b0, acc, 0, 0, 0);
    acc = __builtin_amdgcn_mfma_f32_32x32x16_bf16(a1, b0, acc, 0, 0, 0);
    acc = __builtin_amdgcn_mfma_f32_32x32x16_bf16(a0, b1, acc, 0, 0, 0);
  }
  int col = blockIdx.x * 64 + wn * 32 + (lane & 31);
  int rowb = blockIdx.y * 64 + wm * 32;
  float bv = bias ? bias[col] : 0.f;
#pragma unroll
  for (int j = 0; j < 16; ++j) {
    int row = rowb + (j & 3) + 8 * (j >> 2) + 4 * (lane >> 5);
    float v = acc[j] + bv;
    size_t o = (size_t)row * ldc + col;
    if (outf) outf[o] = v;
    if (outhi) { bf16 h = (bf16)v; outhi[o] = h; outlo[o] = (bf16)(v - (float)h); }
  }
}

// ---------------- main scan kernel ----------------

// direct 64-flag poll (shallow fallback only)
__device__ __forceinline__ void wave_poll(const u32* f, int lane, unsigned tgt) {
  const u32* p = f + lane * FLAG_STRIDE;
  for (;;) {
    unsigned v = __hip_atomic_load(p, __ATOMIC_RELAXED, __HIP_MEMORY_SCOPE_AGENT);
    if (__all((int)(v >= tgt))) break;
    __builtin_amdgcn_s_sleep(2);
  }
  asm volatile("" ::: "memory");
}

// single-relay-line poll: all 64 lanes load same address -> one L3 transaction
__device__ __forceinline__ void relay_poll(const u32* rel, int line, unsigned tgt) {
  const u32* p = rel + line * FLAG_STRIDE;
  while (__hip_atomic_load(p, __ATOMIC_RELAXED, __HIP_MEMORY_SCOPE_AGENT) < tgt)
    __builtin_amdgcn_s_sleep(2);
  asm volatile("" ::: "memory");   // no load may be hoisted above the poll
}

// L2-bypassing 16B ring load (two agent-scope relaxed b64 loads)
union B16U { u64 q[2]; bf16x8 v; };
__device__ __forceinline__ bf16x8 ld_bypass(const bf16* p) {
  const u64* q = (const u64*)p;
  B16U u;
  u.q[0] = __hip_atomic_load(q,     __ATOMIC_RELAXED, __HIP_MEMORY_SCOPE_AGENT);
  u.q[1] = __hip_atomic_load(q + 1, __ATOMIC_RELAXED, __HIP_MEMORY_SCOPE_AGENT);
  return u.v;
}

template<bool DEEP>
__device__ __forceinline__ bf16x8 ld_ring(const bf16* p) {
  if constexpr (DEEP) return *(const bf16x8*)p;   // write-once address: cached load is fresh
  else return ld_bypass(p);
}

__device__ __forceinline__ float fast_sigmoid(float z) {
  return 1.f / (1.f + __expf(-z));
}
__device__ __forceinline__ float fast_tanh(float z) {
  z = fminf(fmaxf(z, -20.f), 20.f);
  float e2 = __expf(-2.f * z);
  return (1.f - e2) / (1.f + e2);
}

// grid 130 (DEEP): blocks 0..63 stage 0, 64..127 stage 1, 128..129 aggregators.
// Aggregator k: sole reader of stage-k's 64 producer flags (one lane per line);
// publishes observed step s to N_RELAYk padded relay lines. Consumer waves poll
// ONE relay line each (<=8 reader-waves per line) -> bounded L3 same-line fan-in.
template<bool DEEP>
__global__ __launch_bounds__(256, 1) void k_scan(
    const bf16* __restrict__ xhi, const bf16* __restrict__ xlo,
    const bf16* __restrict__ Wm0hH, const bf16* __restrict__ Wm0hL,
    const bf16* __restrict__ Whc0H, const bf16* __restrict__ Whc0L,
    const bf16* __restrict__ Wx0H, const bf16* __restrict__ Wx0L,
    const bf16* __restrict__ Wm1hH, const bf16* __restrict__ Wm1hL,
    const bf16* __restrict__ Whc1H, const bf16* __restrict__ Whc1L,
    const bf16* __restrict__ Wx1H, const bf16* __restrict__ Wx1L,
    const float* __restrict__ gm0f, const float* __restrict__ ghb0f, const float* __restrict__ bx0,
    const float* __restrict__ gm1f, const float* __restrict__ ghb1f, const float* __restrict__ bx1,
    bf16* __restrict__ h0ring,
    bf16* __restrict__ h1ring,
    u32* __restrict__ flags0, u32* __restrict__ flags1,
    u32* __restrict__ relay0, u32* __restrict__ relay1,
    float* __restrict__ out) {
  __shared__ __align__(16) float RedH[32][68];
  __shared__ __align__(16) float RedX[32][68];
  __shared__ float gmL[64][8];
  __shared__ float ghbL[3][64][8];
  __shared__ float bxL[24];

  const int tid = threadIdx.x;
  const int wave = tid >> 6, lane = tid & 63;

  if constexpr (DEEP) {
    if (blockIdx.x >= 128) {         // aggregator blocks (no barriers in this path)
      if (wave != 0) return;
      const int which = (int)blockIdx.x - 128;
      const u32* f = which ? flags1 : flags0;
      u32* rel = which ? relay1 : relay0;
      const int nrel = which ? N_RELAY1 : N_RELAY0;
      for (unsigned s = 1; s <= (unsigned)NT; ++s) {
        for (;;) {
          unsigned v = __hip_atomic_load(f + lane * FLAG_STRIDE, __ATOMIC_RELAXED,
                                         __HIP_MEMORY_SCOPE_AGENT);
          if (__all((int)(v >= s))) break;
          __builtin_amdgcn_s_sleep(1);
        }
        if (lane < nrel)
          __hip_atomic_store(rel + lane * FLAG_STRIDE, s, __ATOMIC_RELAXED,
                             __HIP_MEMORY_SCOPE_AGENT);
      }
      return;
    }
  }

  const bool s1 = blockIdx.x >= 64;
  const int w = s1 ? (int)blockIdx.x - 64 : (int)blockIdx.x;
  const int cb = w * 8;

  const float* gmf = s1 ? gm1f : gm0f;
  const float* ghbf = s1 ? ghb1f : ghb0f;
  const float* bxv = s1 ? bx1 : bx0;

  for (int i = tid; i < 512; i += 256) gmL[i >> 3][i & 7] = gmf[(i >> 3) * 512 + cb + (i & 7)];
  for (int i = tid; i < 1536; i += 256) {
    int g = i / 512, j = i - g * 512;
    ghbL[g][j >> 3][j & 7] = ghbf[(j >> 3) * 1536 + g * 512 + cb + (j & 7)];
  }
  if (tid < 24) bxL[tid] = bxv[(tid >> 3) * 512 + cb + (tid & 7)];
  // gmL/ghbL/bxL are first read after the mid-step barrier, so no barrier needed here.

  const bool isH = wave < 2;   // waves 0,1: h-recurrence matmul; 2,3: x-path matmul
  const int mt = wave & 1;     // M-tile (batch rows 32*mt..)
  const int n = lane & 31;     // B column (packed gate row)
  const int kk8 = (lane >> 5) * 8;
  const int arow = mt * 32 + n;

  // ---- one-time: B fragments (hi+lo) into registers ----
  bf16x8 Bhi[32], Blo[32];
  bf16x8 zz;
#pragma unroll
  for (int i = 0; i < 8; ++i) zz[i] = (bf16)0.f;

  if (isH) {
    const bf16 *WH, *WL;
    size_t roff;
    if (n < 8) {
      WH = s1 ? Wm1hH : Wm0hH; WL = s1 ? Wm1hL : Wm0hL;
      roff = (size_t)(cb + n) * 512;
    } else {
      WH = s1 ? Whc1H : Whc0H; WL = s1 ? Whc1L : Whc0L;
      roff = (size_t)(((n >> 3) - 1) * 512 + cb + (n & 7)) * 512;
    }
#pragma unroll
    for (int ks = 0; ks < 32; ++ks) {
      Bhi[ks] = *(const bf16x8*)(WH + roff + ks * 16 + kk8);
      Blo[ks] = *(const bf16x8*)(WL + roff + ks * 16 + kk8);
    }
  } else if (s1) {
    size_t roff = n < 24 ? (size_t)((n >> 3) * 512 + cb + (n & 7)) * 512 : 0;
    bool val = n < 24;
#pragma unroll
    for (int ks = 0; ks < 32; ++ks) {
      bf16x8 bh = *(const bf16x8*)(Wx1H + roff + ks * 16 + kk8);
      bf16x8 bl = *(const bf16x8*)(Wx1L + roff + ks * 16 + kk8);
      Bhi[ks] = val ? bh : zz;
      Blo[ks] = val ? bl : zz;
    }
  } else {
    size_t roff = n < 24 ? (size_t)((n >> 3) * 512 + cb + (n & 7)) * 256 : 0;
    bool val = n < 24;
#pragma unroll
    for (int ks = 0; ks < 16; ++ks) {
      bf16x8 bh = *(const bf16x8*)(Wx0H + roff + ks * 16 + kk8);
      bf16x8 bl = *(const bf16x8*)(Wx0L + roff + ks * 16 + kk8);
      Bhi[ks] = val ? bh : zz;
      Blo[ks] = val ? bl : zz;
    }
  }

  const u32* selfF = s1 ? flags1 : flags0;
  const u32* othF  = s1 ? flags0 : flags1;
  u32* myflag = (s1 ? flags1 : flags0) + w * FLAG_STRIDE;
  const int rl0 = (w + (wave & 1) * 16 + (wave >> 1) * 8) & (N_RELAY0 - 1);
  const int rl1 = (w + wave * 4) & (N_RELAY1 - 1);

  const int gb = tid >> 2, cp = tid & 3;  // gate phase: thread -> (batch gb, col pair cp)

#pragma unroll 1
  for (int t = 0; t < NT; ++t) {
    if constexpr (DEEP) {
      // each wave polls exactly the condition ITS loads require, on ONE relay line
      if (isH) {
        if (t > 0) relay_poll(s1 ? relay1 : relay0, s1 ? rl1 : rl0, (unsigned)t);
      } else if (s1) {
        relay_poll(relay0, rl0, (unsigned)(t + 1));              // h0[t] ready
      }  // stage-0 x-waves: no dependency
    } else {
      if (wave == 0) {
        if (t > 0) wave_poll(selfF, lane, (unsigned)t);
      } else if (wave == 1) {
        if (s1) wave_poll(othF, lane, (unsigned)(t + 1));
        else if (t >= 4) wave_poll(othF, lane, (unsigned)(t - 3)); // ring backpressure
      }
      __syncthreads();
    }

    f32x16 acc;
#pragma unroll
    for (int i = 0; i < 16; ++i) acc[i] = 0.f;

    if (isH || s1) {
      // A = h-state (hi plane, lo plane at +32768), K = 512
      const bf16* Ah;
      if constexpr (DEEP) {
        Ah = (isH ? (s1 ? h1ring : h0ring) + (size_t)t * SLOT_ELEMS      // h[t-1] at slot t
                  : h0ring + (size_t)(t + 1) * SLOT_ELEMS)               // h0[t] at slot t+1
             + arow * 512 + kk8;
      } else {
        if (isH)
          Ah = (s1 ? h1ring + ((t + 1) & 1) * SLOT_ELEMS
                   : h0ring + ((t + 3) & 3) * SLOT_ELEMS) + arow * 512 + kk8;
        else
          Ah = h0ring + (t & 3) * SLOT_ELEMS + arow * 512 + kk8;
      }
#pragma unroll
      for (int ks = 0; ks < 32; ++ks) {
        bf16x8 a0 = ld_ring<DEEP>(Ah + ks * 16);
        bf16x8 a1 = ld_ring<DEEP>(Ah + 32768 + ks * 16);
        acc = __builtin_amdgcn_mfma_f32_32x32x16_bf16(a0, Bhi[ks], acc, 0, 0, 0);
        acc = __builtin_amdgcn_mfma_f32_32x32x16_bf16(a1, Bhi[ks], acc, 0, 0, 0);
        acc = __builtin_amdgcn_mfma_f32_32x32x16_bf16(a0, Blo[ks], acc, 0, 0, 0);
      }
    } else {
      // stage-0 X: A = x[:, t, :] (hi/lo arrays), K = 256 — regular cached loads
      const bf16* Ah = xhi + (size_t)arow * (NT * NIN) + t * NIN + kk8;
      const bf16* Al = xlo + (size_t)arow * (NT * NIN) + t * NIN + kk8;
#pragma unroll
      for (int ks = 0; ks < 16; ++ks) {
        bf16x8 a0 = *(const bf16x8*)(Ah + ks * 16);
        bf16x8 a1 = *(const bf16x8*)(Al + ks * 16);
        acc = __builtin_amdgcn_mfma_f32_32x32x16_bf16(a0, Bhi[ks], acc, 0, 0, 0);
        acc = __builtin_amdgcn_mfma_f32_32x32x16_bf16(a1, Bhi[ks], acc, 0, 0, 0);
        acc = __builtin_amdgcn_mfma_f32_32x32x16_bf16(a0, Blo[ks], acc, 0, 0, 0);
      }
    }

    {  // C fragments -> LDS transpose buffer: Red[packed_col][batch_row]
      float (*Red)[68] = isH ? RedH : RedX;
#pragma unroll
      for (int rg = 0; rg < 4; ++rg) {
        f32x4 v;
        v[0] = acc[4 * rg]; v[1] = acc[4 * rg + 1];
        v[2] = acc[4 * rg + 2]; v[3] = acc[4 * rg + 3];
        *(f32x4*)&Red[n][mt * 32 + rg * 8 + ((lane >> 5) << 2)] = v;
      }
    }
    __syncthreads();

    // gate phase: thread handles (gb, c=2cp) and (gb, c=2cp+1)
    float hv[2];
#pragma unroll
    for (int e = 0; e < 2; ++e) {
      int c = 2 * cp + e;
      float hx = gmL[gb][c] + RedH[c][gb];
      float hr = ghbL[0][gb][c] + RedH[8 + c][gb];
      float hu = ghbL[1][gb][c] + RedH[16 + c][gb];
      float hn = ghbL[2][gb][c] + RedH[24 + c][gb];
      float xr = bxL[c] + RedX[c][gb];
      float xu = bxL[8 + c] + RedX[8 + c][gb];
      float xn = bxL[16 + c] + RedX[16 + c][gb];
      float r = fast_sigmoid(xr + hr);
      float u = fast_sigmoid(xu + hu);
      float nn = fast_tanh(xn + r * hn);
      hv[e] = u * hx + (1.f - u) * nn;
    }
    {
      bf16 h0b = (bf16)hv[0];
      bf16 h1b = (bf16)hv[1];
      bf16 l0b = (bf16)(hv[0] - (float)h0b);
      bf16 l1b = (bf16)(hv[1] - (float)h1b);
      u32 hp = (u32)__builtin_bit_cast(u16, h0b) | ((u32)__builtin_bit_cast(u16, h1b) << 16);
      u32 lp = (u32)__builtin_bit_cast(u16, l0b) | ((u32)__builtin_bit_cast(u16, l1b) << 16);
      bf16* wr;
      if constexpr (DEEP)
        wr = (s1 ? h1ring : h0ring) + (size_t)(t + 1) * SLOT_ELEMS;   // h[t] at slot t+1
      else
        wr = s1 ? h1ring + (t & 1) * SLOT_ELEMS : h0ring + (t & 3) * SLOT_ELEMS;
      u32* whi = (u32*)wr + ((gb * 512 + cb) >> 1) + cp;
      // write-through (agent scope): visible at L3 before the flag below
      __hip_atomic_store(whi, hp, __ATOMIC_RELAXED, __HIP_MEMORY_SCOPE_AGENT);
      __hip_atomic_store(whi + 16384, lp, __ATOMIC_RELAXED, __HIP_MEMORY_SCOPE_AGENT);
    }
    __syncthreads();   // vmcnt(0) drain: all waves' ring stores ack'd before the flag
    if (tid == 0)
      __hip_atomic_store(myflag, (unsigned)(t + 1), __ATOMIC_RELAXED, __HIP_MEMORY_SCOPE_AGENT);
    if (s1) {          // out store off the critical path (regular cached store)
      *(float2*)&out[(size_t)gb * (NT * NH) + (size_t)t * NH + cb + 2 * cp] =
          make_float2(hv[0], hv[1]);
    }
  }
}

// ---------------- host ----------------

extern "C" void kernel_launch(void* const* d_in, const int* in_sizes, int n_in,
                              void* d_out, int out_size, void* d_ws, size_t ws_size,
                              hipStream_t stream) {
  const float* x   = (const float*)d_in[0];
  const float* g   = (const float*)d_in[1];
  const float* Wx0 = (const float*)d_in[2];
  const float* bx0 = (const float*)d_in[3];
  const float* Wh0 = (const float*)d_in[4];
  const float* bh0 = (const float*)d_in[5];
  const float* Wm0 = (const float*)d_in[6];
  const float* bm0 = (const float*)d_in[7];
  const float* Wx1 = (const float*)d_in[8];
  const float* bx1 = (const float*)d_in[9];
  const float* Wh1 = (const float*)d_in[10];
  const float* bh1 = (const float*)d_in[11];
  const float* Wm1 = (const float*)d_in[12];
  const float* bm1 = (const float*)d_in[13];
  float* out = (float*)d_out;

  char* wp = (char*)d_ws;
  auto alloc = [&](size_t bytes) -> char* {
    char* p = wp;
    wp += (bytes + 255) & ~(size_t)255;
    return p;
  };
  bf16* x_hi   = (bf16*)alloc((size_t)NB * NT * NIN * 2);
  bf16* x_lo   = (bf16*)alloc((size_t)NB * NT * NIN * 2);
  bf16* Wx0H   = (bf16*)alloc(1536 * 256 * 2);
  bf16* Wx0L   = (bf16*)alloc(1536 * 256 * 2);
  bf16* Wx1H   = (bf16*)alloc(1536 * 512 * 2);
  bf16* Wx1L   = (bf16*)alloc(1536 * 512 * 2);
  bf16* Wh0H   = (bf16*)alloc(1536 * 512 * 2);
  bf16* Wh0L   = (bf16*)alloc(1536 * 512 * 2);
  bf16* Wh1H   = (bf16*)alloc(1536 * 512 * 2);
  bf16* Wh1L   = (bf16*)alloc(1536 * 512 * 2);
  bf16* Wm0hH  = (bf16*)alloc(512 * 512 * 2);
  bf16* Wm0hL  = (bf16*)alloc(512 * 512 * 2);
  bf16* Wm0tH  = (bf16*)alloc(512 * 512 * 2);
  bf16* Wm0tL  = (bf16*)alloc(512 * 512 * 2);
  bf16* Wg0H   = (bf16*)alloc(512 * 512 * 2);
  bf16* Wg0L   = (bf16*)alloc(512 * 512 * 2);
  bf16* Wm1hH  = (bf16*)alloc(512 * 512 * 2);
  bf16* Wm1hL  = (bf16*)alloc(512 * 512 * 2);
  bf16* Wm1tH  = (bf16*)alloc(512 * 512 * 2);
  bf16* Wm1tL  = (bf16*)alloc(512 * 512 * 2);
  bf16* Wg1H   = (bf16*)alloc(512 * 512 * 2);
  bf16* Wg1L   = (bf16*)alloc(512 * 512 * 2);
  bf16* gH     = (bf16*)alloc(64 * 512 * 2);
  bf16* gL     = (bf16*)alloc(64 * 512 * 2);
  float* gm0f  = (float*)alloc(64 * 512 * 4);
  float* gm1f  = (float*)alloc(64 * 512 * 4);
  bf16* gm0H   = (bf16*)alloc(64 * 512 * 2);
  bf16* gm0L   = (bf16*)alloc(64 * 512 * 2);
  bf16* gm1H   = (bf16*)alloc(64 * 512 * 2);
  bf16* gm1L   = (bf16*)alloc(64 * 512 * 2);
  float* ghb0f = (float*)alloc(64 * 1536 * 4);
  float* ghb1f = (float*)alloc(64 * 1536 * 4);
  bf16* Whc0H  = (bf16*)alloc(1536 * 512 * 2);
  bf16* Whc0L  = (bf16*)alloc(1536 * 512 * 2);
  bf16* Whc1H  = (bf16*)alloc(1536 * 512 * 2);
  bf16* Whc1L  = (bf16*)alloc(1536 * 512 * 2);
  bf16* h0ring = (bf16*)alloc(4 * (size_t)SLOT_ELEMS * 2);   // 524288 B (shallow)
  bf16* h1ring = (bf16*)alloc(2 * (size_t)SLOT_ELEMS * 2);   // 262144 B (shallow)
  u32* flags   = (u32*)alloc(2 * 64 * FLAG_STRIDE * 4);      // 32768 B, line-padded
  u32* relays  = (u32*)alloc((N_RELAY0 + N_RELAY1) * FLAG_STRIDE * 4);  // 6144 B, after flags
  u32* flags0 = flags;
  u32* flags1 = flags + 64 * FLAG_STRIDE;
  u32* relay0 = relays;
  u32* relay1 = relays + N_RELAY0 * FLAG_STRIDE;

  // deep rings (write-once slots) if the workspace is big enough
  size_t base_end = (size_t)(wp - (char*)d_ws);
  bool deep = (base_end + 2 * DEEP_RING_BYTES) <= ws_size;
  bf16 *h0deep = nullptr, *h1deep = nullptr;
  if (deep) {
    h0deep = (bf16*)alloc(DEEP_RING_BYTES);
    h1deep = (bf16*)alloc(DEEP_RING_BYTES);
  }

  // conversions (hi/lo splits)
  k_cvt_hl<<<2048, 256, 0, stream>>>((const float4*)x, (bf16x4*)x_hi, (bf16x4*)x_lo,
                                     (NB * NT * NIN) / 4);
  k_cvt_hl<<<384, 256, 0, stream>>>((const float4*)Wx0, (bf16x4*)Wx0H, (bf16x4*)Wx0L,
                                    (1536 * 256) / 4);
  k_cvt_hl<<<768, 256, 0, stream>>>((const float4*)Wx1, (bf16x4*)Wx1H, (bf16x4*)Wx1L,
                                    (1536 * 512) / 4);
  k_cvt_hl<<<768, 256, 0, stream>>>((const float4*)Wh0, (bf16x4*)Wh0H, (bf16x4*)Wh0L,
                                    (1536 * 512) / 4);
  k_cvt_hl<<<768, 256, 0, stream>>>((const float4*)Wh1, (bf16x4*)Wh1H, (bf16x4*)Wh1L,
                                    (1536 * 512) / 4);
  k_cvt_hl<<<32, 256, 0, stream>>>((const float4*)g, (bf16x4*)gH, (bf16x4*)gL,
                                   (64 * 512) / 4);
  k_cvt_wm<<<1024, 256, 0, stream>>>(Wm0, Wm0hH, Wm0hL, Wm0tH, Wm0tL, Wg0H, Wg0L);
  k_cvt_wm<<<1024, 256, 0, stream>>>(Wm1, Wm1hH, Wm1hL, Wm1tH, Wm1tL, Wg1H, Wg1L);

  // gm = g @ Wm[:, :G]^T + bm  (f32 + hi/lo)
  k_gemm<<<dim3(8, 1), 256, 0, stream>>>(gH, gL, 512, Wg0H, Wg0L, 512, bm0,
                                         gm0f, gm0H, gm0L, 512, 512);
  k_gemm<<<dim3(8, 1), 256, 0, stream>>>(gH, gL, 512, Wg1H, Wg1L, 512, bm1,
                                         gm1f, gm1H, gm1L, 512, 512);
  // ghb = gm @ Wh^T + bh  (f32)
  k_gemm<<<dim3(24, 1), 256, 0, stream>>>(gm0H, gm0L, 512, Wh0H, Wh0L, 512, bh0,
                                          ghb0f, (bf16*)nullptr, (bf16*)nullptr, 1536, 512);
  k_gemm<<<dim3(24, 1), 256, 0, stream>>>(gm1H, gm1L, 512, Wh1H, Wh1L, 512, bh1,
                                          ghb1f, (bf16*)nullptr, (bf16*)nullptr, 1536, 512);
  // Whc = Wh @ Wmh  (hi/lo); B[n][k] = Wmh[k][n] = WmhT
  k_gemm<<<dim3(8, 24), 256, 0, stream>>>(Wh0H, Wh0L, 512, Wm0tH, Wm0tL, 512,
                                          (const float*)nullptr, (float*)nullptr,
                                          Whc0H, Whc0L, 512, 512);
  k_gemm<<<dim3(8, 24), 256, 0, stream>>>(Wh1H, Wh1L, 512, Wm1tH, Wm1tL, 512,
                                          (const float*)nullptr, (float*)nullptr,
                                          Whc1H, Whc1L, 512, 512);

  if (deep) {
    // zero flags + relays (contiguous) + slot 0 of each deep ring (h[-1] = 0)
    hipMemsetAsync(flags, 0, 2 * 64 * FLAG_STRIDE * 4 + (N_RELAY0 + N_RELAY1) * FLAG_STRIDE * 4,
                   stream);
    hipMemsetAsync(h0deep, 0, SLOT_ELEMS * 2, stream);
    hipMemsetAsync(h1deep, 0, SLOT_ELEMS * 2, stream);
    k_scan<true><<<130, 256, 0, stream>>>(
        x_hi, x_lo,
        Wm0hH, Wm0hL, Whc0H, Whc0L, Wx0H, Wx0L,
        Wm1hH, Wm1hL, Whc1H, Whc1L, Wx1H, Wx1L,
        gm0f, ghb0f, bx0, gm1f, ghb1f, bx1,
        h0deep, h1deep, flags0, flags1, relay0, relay1, out);
  } else {
    // zero shallow rings + flags + relays (contiguous in ws)
    hipMemsetAsync(h0ring, 0, 524288 + 262144 + 32768 + 6144, stream);
    k_scan<false><<<128, 256, 0, stream>>>(
        x_hi, x_lo,
        Wm0hH, Wm0hL, Whc0H, Whc0L, Wx0H, Wx0L,
        Wm1hH, Wm1hL, Whc1H, Whc1L, Wx1H, Wx1L,
        gm0f, ghb0f, bx0, gm1f, ghb1f, bx1,
        h0ring, h1ring, flags0, flags1, relay0, relay1, out);
  }
}